// Round 5
// baseline (163.316 us; speedup 1.0000x reference)
//
#include <hip/hip_runtime.h>

// CommSlave — Round 5: prep kernel (bf16 pre-transposed weights in module
// memory) + wave-local fused MFMA kernel with no weight staging in LDS.
// Block = 256 thr = 4 waves; wave = 16 rows = 2 attention groups. Grid = 1024.
// A-frags (obs, h_in) load straight from global fp32 (lane=row, 32 B contig);
// B-frags are 16-B uint4 loads from prepped bf16 images (L1/L2-hot).
// LDS only for x / h_out bf16 (A-frags of later GEMMs) + fp32 scratch.
// Fragment mappings (verified round 4): A[m=lane&15][k=quad*8+j];
// B[k][n=lane&15] stored as [n][k]; C/D col=lane&15, row=quad*4+reg.

#define NACT 14
#define BTOT 65536

typedef unsigned int  u32;
typedef unsigned short u16;
using short8 = __attribute__((ext_vector_type(8))) short;
using f32x4  = __attribute__((ext_vector_type(4))) float;

// ---- prepped weight images (u16 offsets), module device memory ----
#define ENCB 0        // [n=64][k pad 264]  B[k][n] = encW[k][n]
#define WIHB 16896    // [n=192][k pad 72]  B[k][n] = Wih[n][k]
#define WHHB 30720    // [n=192][k pad 72]
#define QKVB 44544    // [n=96][k pad 72]   rows 0-31 qW^T*(1/sqrt32), 32-63 kW^T, 64-95 vW^T
#define DECB 51456    // [n=16][k pad 104]  B[k][n] = decW[k][n], zero-padded
#define WTOT 53120

__device__ u16   g_wbuf[WTOT];
__device__ float g_bias[256];   // [0,64): bih+bhh (r) ; [64,128): bih+bhh (z) ; [128,192): bih_n ; [192,256): bhh_n

__device__ __forceinline__ u32 f2bf(float f){
  u32 x = __float_as_uint(f);
  return (x + 0x7fffu + ((x >> 16) & 1u)) >> 16;   // RNE
}
__device__ __forceinline__ u32 pk2(float a, float b){ return f2bf(a) | (f2bf(b) << 16); }
__device__ __forceinline__ float sigm(float x){ return 1.0f / (1.0f + __expf(-x)); }
__device__ __forceinline__ float tanhp(float x){ return 1.0f - 2.0f / (__expf(2.0f * x) + 1.0f); }
__device__ __forceinline__ short8 as_s8(uint4 v){ union { uint4 u; short8 s; } x; x.u = v; return x.s; }

#define MFMA16(a,b,c) __builtin_amdgcn_mfma_f32_16x16x32_bf16((a),(b),(c),0,0,0)

// ======================= prep: fp32 -> bf16 transposed images ================
__global__ void prep(const float* __restrict__ encW, const float* __restrict__ Wih,
                     const float* __restrict__ Whh,  const float* __restrict__ qW,
                     const float* __restrict__ kW,   const float* __restrict__ vW,
                     const float* __restrict__ decW, const float* __restrict__ bih,
                     const float* __restrict__ bhh)
{
  int i = blockIdx.x * 256 + threadIdx.x;
  if (blockIdx.x == 0) {
    int n = threadIdx.x & 63, g = threadIdx.x >> 6;
    float v;
    if      (g == 0) v = bih[n]       + bhh[n];
    else if (g == 1) v = bih[64 + n]  + bhh[64 + n];
    else if (g == 2) v = bih[128 + n];
    else             v = bhh[128 + n];
    g_bias[threadIdx.x] = v;
  }
  if (i >= WTOT) return;
  float val = 0.f;
  if (i < WIHB)      { int n = i / 264, k = i % 264;            if (k < 256) val = encW[k * 64 + n]; }
  else if (i < WHHB) { int j = i - WIHB; int n = j / 72, k = j % 72; if (k < 64) val = Wih[n * 64 + k]; }
  else if (i < QKVB) { int j = i - WHHB; int n = j / 72, k = j % 72; if (k < 64) val = Whh[n * 64 + k]; }
  else if (i < DECB) { int j = i - QKVB; int n = j / 72, k = j % 72;
    if (k < 64) { int m = n >> 5, nn = n & 31;
      val = (m == 0) ? qW[k * 32 + nn] * 0.17677669529663687f
          : (m == 1) ? kW[k * 32 + nn] : vW[k * 32 + nn]; } }
  else { int j = i - DECB; int n = j / 104, k = j % 104; if (n < 14 && k < 96) val = decW[k * 14 + n]; }
  g_wbuf[i] = (u16)f2bf(val);
}

// ======================= main fused kernel ===================================
// LDS (46080 B): X bf16 [64][72] @u16 0 ; H bf16 [64][72] @u16 4608 ;
// SC fp32 scratch @byte 18432 : per-wave S [16][68] or ATT [16][108].
__global__ __launch_bounds__(256, 3)
void commslave_main(const float* __restrict__ obs,  const float* __restrict__ hid,
                    const float* __restrict__ encb, const float* __restrict__ vb,
                    const float* __restrict__ decb, float* __restrict__ out)
{
  __shared__ __align__(16) u16 ldsU[23040];

  const int tid  = threadIdx.x;
  const int lane = tid & 63;
  const int w    = tid >> 6;
  const int quad = lane >> 4;
  const int l16  = lane & 15;
  const int M0   = 16 * w;
  const int gr   = blockIdx.x * 64 + M0;     // wave's global base row

  float* Sf = (float*)(ldsU + 9216) + w * (16 * 68);   // [16][68]
  float* Af = (float*)(ldsU + 9216) + w * (16 * 108);  // [16][108] (later phase)

  // ---------------- enc: x = relu(obs @ encW + encb) -------------------------
  f32x4 ce[4];
  #pragma unroll
  for (int t = 0; t < 4; t++) { float bv = encb[16 * t + l16]; ce[t] = (f32x4){bv, bv, bv, bv}; }
  #pragma unroll
  for (int ks = 0; ks < 8; ks++) {
    const float* ap = obs + (size_t)(gr + l16) * 256 + ks * 32 + quad * 8;
    float4 a0 = *(const float4*)ap, a1 = *(const float4*)(ap + 4);
    short8 a = as_s8(make_uint4(pk2(a0.x, a0.y), pk2(a0.z, a0.w), pk2(a1.x, a1.y), pk2(a1.z, a1.w)));
    #pragma unroll
    for (int t = 0; t < 4; t++) {
      short8 b = as_s8(*(const uint4*)&g_wbuf[ENCB + (16 * t + l16) * 264 + ks * 32 + quad * 8]);
      ce[t] = MFMA16(a, b, ce[t]);
    }
  }
  #pragma unroll
  for (int t = 0; t < 4; t++)
    #pragma unroll
    for (int r = 0; r < 4; r++)
      Sf[(quad * 4 + r) * 68 + 16 * t + l16] = fmaxf(ce[t][r], 0.f);
  // wave-local repack: S fp32 -> X bf16 [row][k] (b128 aligned stores)
  #pragma unroll
  for (int i = 0; i < 2; i++) {
    int c = lane + 64 * i, lr = c >> 3, j = c & 7;
    const float* sp = &Sf[lr * 68 + 8 * j];
    float4 v0 = *(const float4*)sp, v1 = *(const float4*)(sp + 4);
    *(uint4*)&ldsU[(M0 + lr) * 72 + 8 * j] =
        make_uint4(pk2(v0.x, v0.y), pk2(v0.z, v0.w), pk2(v1.x, v1.y), pk2(v1.z, v1.w));
  }
  __syncthreads();   // fence: X uint4 writes -> short8 frag reads

  // ---------------- GRU ------------------------------------------------------
  short8 ax[2], ah[2];
  #pragma unroll
  for (int ks = 0; ks < 2; ks++) {
    ax[ks] = *(const short8*)&ldsU[(M0 + l16) * 72 + ks * 32 + quad * 8];
    const float* hp = hid + (size_t)(gr + l16) * 64 + ks * 32 + quad * 8;
    float4 h0 = *(const float4*)hp, h1 = *(const float4*)(hp + 4);
    ah[ks] = as_s8(make_uint4(pk2(h0.x, h0.y), pk2(h0.z, h0.w), pk2(h1.x, h1.y), pk2(h1.z, h1.w)));
  }
  #pragma unroll
  for (int u = 0; u < 4; u++) {
    f32x4 g6[6];
    #pragma unroll
    for (int t = 0; t < 6; t++) g6[t] = (f32x4){0.f, 0.f, 0.f, 0.f};
    #pragma unroll
    for (int g = 0; g < 3; g++) {
      int row = 64 * g + 16 * u + l16;
      #pragma unroll
      for (int ks = 0; ks < 2; ks++) {
        short8 bi = as_s8(*(const uint4*)&g_wbuf[WIHB + row * 72 + ks * 32 + quad * 8]);
        g6[g] = MFMA16(ax[ks], bi, g6[g]);
        short8 bh = as_s8(*(const uint4*)&g_wbuf[WHHB + row * 72 + ks * 32 + quad * 8]);
        g6[3 + g] = MFMA16(ah[ks], bh, g6[3 + g]);
      }
    }
    int nc = 16 * u + l16;
    float brz = g_bias[nc], bzz = g_bias[64 + nc], bni = g_bias[128 + nc], bnh = g_bias[192 + nc];
    #pragma unroll
    for (int r = 0; r < 4; r++) {
      float hp = hid[(size_t)(gr + quad * 4 + r) * 64 + nc];
      float rg = sigm(g6[0][r] + g6[3][r] + brz);
      float zg = sigm(g6[1][r] + g6[4][r] + bzz);
      float nn = tanhp(g6[2][r] + bni + rg * (g6[5][r] + bnh));
      Sf[(quad * 4 + r) * 68 + nc] = (1.f - zg) * nn + zg * hp;
    }
  }
  // repack h_out: S fp32 -> H bf16 + coalesced fp32 global store
  float* outH = out + (size_t)BTOT * NACT;
  #pragma unroll
  for (int i = 0; i < 2; i++) {
    int c = lane + 64 * i, lr = c >> 3, j = c & 7;
    const float* sp = &Sf[lr * 68 + 8 * j];
    float4 v0 = *(const float4*)sp, v1 = *(const float4*)(sp + 4);
    *(uint4*)&ldsU[4608 + (M0 + lr) * 72 + 8 * j] =
        make_uint4(pk2(v0.x, v0.y), pk2(v0.z, v0.w), pk2(v1.x, v1.y), pk2(v1.z, v1.w));
    *(float4*)(outH + (size_t)(gr + lr) * 64 + 8 * j)     = v0;
    *(float4*)(outH + (size_t)(gr + lr) * 64 + 8 * j + 4) = v1;
  }
  __syncthreads();   // fence: H uint4 writes -> short8 frag reads

  // ---------------- q,k,v ----------------------------------------------------
  short8 hx[2];
  #pragma unroll
  for (int ks = 0; ks < 2; ks++)
    hx[ks] = *(const short8*)&ldsU[4608 + (M0 + l16) * 72 + ks * 32 + quad * 8];
  f32x4 cq[6];
  #pragma unroll
  for (int t = 0; t < 6; t++) {
    float bv = (t >= 4) ? vb[16 * (t - 4) + l16] : 0.f;
    cq[t] = (f32x4){bv, bv, bv, bv};
  }
  #pragma unroll
  for (int ks = 0; ks < 2; ks++)
    #pragma unroll
    for (int t = 0; t < 6; t++) {
      short8 b = as_s8(*(const uint4*)&g_wbuf[QKVB + (16 * t + l16) * 72 + ks * 32 + quad * 8]);
      cq[t] = MFMA16(hx[ks], b, cq[t]);
    }
  #pragma unroll
  for (int t = 0; t < 6; t++)
    #pragma unroll
    for (int r = 0; r < 4; r++) {
      float v = cq[t][r];
      if (t >= 4) v = fmaxf(v, 0.f);
      Af[(quad * 4 + r) * 108 + 16 * t + l16] = v;   // q (pre-scaled), k, v
    }

  // ---------------- attention (wave-local; 4 lanes per row) ------------------
  {
    const int r_l = lane >> 2, s4 = lane & 3;
    const int gb = r_l & 8, ri = r_l & 7;
    const float* fq = &Af[r_l * 108];
    float sc[2];
    #pragma unroll
    for (int jj = 0; jj < 2; jj++) {
      int j = s4 + 4 * jj;
      const float* fk = &Af[(gb + j) * 108 + 32];
      float d = 0.f;
      #pragma unroll
      for (int a4 = 0; a4 < 32; a4 += 4) {
        float4 q4 = *(const float4*)&fq[a4];
        float4 k4 = *(const float4*)&fk[a4];
        d += q4.x * k4.x + q4.y * k4.y + q4.z * k4.z + q4.w * k4.w;
      }
      sc[jj] = (j == ri) ? -1e30f : d;
    }
    float m = fmaxf(sc[0], sc[1]);
    m = fmaxf(m, __shfl_xor(m, 1));
    m = fmaxf(m, __shfl_xor(m, 2));
    float p0 = (s4     == ri) ? 0.f : __expf(sc[0] - m);
    float p1 = (s4 + 4 == ri) ? 0.f : __expf(sc[1] - m);
    float sum = p0 + p1;
    sum += __shfl_xor(sum, 1);
    sum += __shfl_xor(sum, 2);
    float inv = 1.f / sum;
    Af[r_l * 108 + 96 + s4]  = p0 * inv;
    Af[r_l * 108 + 100 + s4] = p1 * inv;
    float xa[8] = {0, 0, 0, 0, 0, 0, 0, 0};
    #pragma unroll
    for (int j = 0; j < 8; j++) {
      float aj = Af[r_l * 108 + 96 + j];
      const float* fv = &Af[(gb + j) * 108 + 64 + 8 * s4];
      float4 w0 = *(const float4*)fv, w1 = *(const float4*)(fv + 4);
      xa[0] += aj * w0.x; xa[1] += aj * w0.y; xa[2] += aj * w0.z; xa[3] += aj * w0.w;
      xa[4] += aj * w1.x; xa[5] += aj * w1.y; xa[6] += aj * w1.z; xa[7] += aj * w1.w;
    }
    *(uint4*)&ldsU[(M0 + r_l) * 72 + 8 * s4] =      // xatt bf16 into X cols 0..31
        make_uint4(pk2(xa[0], xa[1]), pk2(xa[2], xa[3]), pk2(xa[4], xa[5]), pk2(xa[6], xa[7]));
  }
  __syncthreads();   // fence: xatt uint4 writes -> short8 frag reads

  // ---------------- dec: [h_out | xatt] @ decW + decb ------------------------
  {
    float db = (l16 < NACT) ? decb[l16] : 0.f;
    f32x4 co = (f32x4){db, db, db, db};
    #pragma unroll
    for (int ks = 0; ks < 2; ks++) {
      short8 a = *(const short8*)&ldsU[4608 + (M0 + l16) * 72 + ks * 32 + quad * 8];
      short8 b = as_s8(*(const uint4*)&g_wbuf[DECB + l16 * 104 + ks * 32 + quad * 8]);
      co = MFMA16(a, b, co);
    }
    short8 a2 = *(const short8*)&ldsU[(M0 + l16) * 72 + quad * 8];
    short8 b2 = as_s8(*(const uint4*)&g_wbuf[DECB + l16 * 104 + 64 + quad * 8]);
    co = MFMA16(a2, b2, co);
    if (l16 < NACT) {
      #pragma unroll
      for (int r = 0; r < 4; r++)
        out[(size_t)(gr + quad * 4 + r) * NACT + l16] = co[r];
    }
  }
}

extern "C" void kernel_launch(void* const* d_in, const int* in_sizes, int n_in,
                              void* d_out, int out_size, void* d_ws, size_t ws_size,
                              hipStream_t stream) {
  (void)in_sizes; (void)n_in; (void)d_ws; (void)ws_size; (void)out_size;
  const float* obs  = (const float*)d_in[0];
  const float* hid  = (const float*)d_in[1];
  const float* encW = (const float*)d_in[2];
  const float* encb = (const float*)d_in[3];
  const float* Wih  = (const float*)d_in[4];
  const float* Whh  = (const float*)d_in[5];
  const float* bih  = (const float*)d_in[6];
  const float* bhh  = (const float*)d_in[7];
  const float* qW   = (const float*)d_in[8];
  const float* kW   = (const float*)d_in[9];
  const float* vW   = (const float*)d_in[10];
  const float* vb   = (const float*)d_in[11];
  const float* decW = (const float*)d_in[12];
  const float* decb = (const float*)d_in[13];
  float* out = (float*)d_out;

  prep<<<(WTOT + 255) / 256, 256, 0, stream>>>(encW, Wih, Whh, qW, kW, vW, decW, bih, bhh);
  commslave_main<<<BTOT / 64, 256, 0, stream>>>(obs, hid, encb, vb, decb, out);
}